// Round 11
// baseline (259.915 us; speedup 1.0000x reference)
//
#include <hip/hip_runtime.h>
#include <hip/hip_fp16.h>

using half8 = __attribute__((ext_vector_type(8))) _Float16;
using f32x4 = __attribute__((ext_vector_type(4))) float;

// ============ bucketed CSR build ============
// bucket b = dst >> 8 (256 nodes/bucket, NB=391); region r = blockIdx%8 edge slice.
// ebuf order: bucket-major, region-minor. One block later owns one whole bucket.
// NEW (R11): csr rows are sorted by src shard (src>>14) so the gather kernels walk
// the 12.8MB table in ~2MB phases -> L2-resident working set.

__global__ __launch_bounds__(256) void k_bhist(const int* __restrict__ dst, int E, int Er, int N,
                                               int* __restrict__ bhist) {
    extern __shared__ int h[];  // NB ints
    const int NB = (N + 255) >> 8;
    for (int i = threadIdx.x; i < NB; i += 256) h[i] = 0;
    __syncthreads();
    int r = blockIdx.x & 7, j = blockIdx.x >> 3;
    int e0 = r * Er + j * 4096;
    int e1 = min(min((r + 1) * Er, E), e0 + 4096);
    for (int e = e0 + threadIdx.x; e < e1; e += 256) {
        int d = dst[e];
        d = ((unsigned)d < (unsigned)N) ? d : 0;
        atomicAdd(&h[d >> 8], 1);
    }
    __syncthreads();
    for (int i = threadIdx.x; i < NB; i += 256)
        if (h[i]) atomicAdd(&bhist[i * 8 + r], h[i]);
}

// exclusive scan of bcur[M], M = NB*8 <= 4096; also emit pristine bucket starts
__global__ void k_bscan(int* __restrict__ bcur, int M, int NB, int E, int* __restrict__ bstart) {
    __shared__ int sd[1024];
    int t = threadIdx.x;
    int v[4];
    int s = 0;
#pragma unroll
    for (int j = 0; j < 4; j++) {
        int i = t * 4 + j;
        v[j] = (i < M) ? bcur[i] : 0;
        s += v[j];
    }
    sd[t] = s;
    __syncthreads();
    for (int off = 1; off < 1024; off <<= 1) {
        int x = (t >= off) ? sd[t - off] : 0;
        __syncthreads();
        sd[t] += x;
        __syncthreads();
    }
    int run = (t == 0) ? 0 : sd[t - 1];
#pragma unroll
    for (int j = 0; j < 4; j++) {
        int i = t * 4 + j;
        if (i < M) bcur[i] = run;
        run += v[j];
    }
    __syncthreads();
    for (int b = t; b <= NB; b += 1024) bstart[b] = (b < NB) ? bcur[b * 8] : E;
}

// partition edges into (bucket,region)-ordered ebuf; tail: fused X->fp16 conversion
__global__ __launch_bounds__(256) void k_part(const int* __restrict__ src, const int* __restrict__ dst,
                                              int E, int Er, int N, int* __restrict__ bcur,
                                              uint2* __restrict__ ebuf,
                                              const float4* __restrict__ X4, int M,
                                              uint2* __restrict__ Xh) {
    __shared__ int lcnt[391], lbase[391];
    const int NB = (N + 255) >> 8;
    int t = threadIdx.x;
    int r = blockIdx.x & 7, jb = blockIdx.x >> 3;
    int e0 = r * Er + jb * 4096;
    int e1 = min(min((r + 1) * Er, E), e0 + 4096);
    int s[16], d[16];
    for (int i = t; i < NB; i += 256) lcnt[i] = 0;
    __syncthreads();
#pragma unroll
    for (int j = 0; j < 16; j++) {
        int e = e0 + j * 256 + t;
        if (e < e1) {
            int dd = dst[e];
            dd = ((unsigned)dd < (unsigned)N) ? dd : 0;  // clamp: consistent everywhere
            d[j] = dd;
            int ss = src[e];
            s[j] = ((unsigned)ss < (unsigned)N) ? ss : 0;  // clamp src too (shard math safety)
            atomicAdd(&lcnt[dd >> 8], 1);
        } else d[j] = -1;
    }
    __syncthreads();
    for (int i = t; i < NB; i += 256)
        lbase[i] = lcnt[i] ? atomicAdd(&bcur[i * 8 + r], lcnt[i]) : 0;
    __syncthreads();
    for (int i = t; i < NB; i += 256) lcnt[i] = 0;
    __syncthreads();
#pragma unroll
    for (int j = 0; j < 16; j++) {
        if (d[j] >= 0) {
            int bk = d[j] >> 8;
            int pos = lbase[bk] + atomicAdd(&lcnt[bk], 1);
            ebuf[pos] = make_uint2((unsigned)s[j], (unsigned)d[j]);
        }
    }
    // fused X -> fp16 streaming conversion (independent work; fills latency bubbles)
    for (int i = blockIdx.x * 256 + t; i < M; i += gridDim.x * 256) {
        float4 v = X4[i];
        __half2 lo = __floats2half2_rn(v.x, v.y);
        __half2 hi = __floats2half2_rn(v.z, v.w);
        uint2 o;
        o.x = *(unsigned*)&lo;
        o.y = *(unsigned*)&hi;
        Xh[i] = o;
    }
}

// one block per bucket: LDS (node x shard) hist -> local scan (global offs = bstart[b] + prefix)
// -> write cnt/offs/dinv -> shard-ordered LDS-cursor CSR scatter (single-L2 window).
// Shard of src = src>>14 (0..6 for N=100000) -> each csr row sorted by src shard.
__global__ __launch_bounds__(256) void k_build(const uint2* __restrict__ ebuf,
                                               const int* __restrict__ bstart, int N,
                                               int* __restrict__ cnt, float* __restrict__ dinv,
                                               int* __restrict__ offs, int* __restrict__ csr) {
    __shared__ int h2[2048];    // (node & 255) * 8 + shard : counts, then starts
    __shared__ int lc2[2048];   // scatter cursors
    __shared__ int sc[256];
    int b = blockIdx.x, t = threadIdx.x;
    int base = b << 8;
#pragma unroll
    for (int i = 0; i < 8; i++) { h2[t * 8 + i] = 0; lc2[t * 8 + i] = 0; }
    __syncthreads();
    int e0 = bstart[b], e1 = bstart[b + 1];
    for (int e = e0 + t; e < e1; e += 256) {
        uint2 p = ebuf[e];
        atomicAdd(&h2[(p.y & 255) * 8 + (p.x >> 14)], 1);
    }
    __syncthreads();
    // thread t owns node base+t: its 8 shard counts are h2[t*8 .. t*8+7]
    int v[8], deg = 0;
#pragma unroll
    for (int i = 0; i < 8; i++) { v[i] = h2[t * 8 + i]; deg += v[i]; }
    sc[t] = deg;
    __syncthreads();
    for (int off = 1; off < 256; off <<= 1) {
        int x = (t >= off) ? sc[t - off] : 0;
        __syncthreads();
        sc[t] += x;
        __syncthreads();
    }
    int lo = e0 + sc[t] - deg;  // global csr offset for node base+t
    int n = base + t;
    if (n < N) {
        cnt[n] = deg;
        offs[n] = lo;
        dinv[n] = rsqrtf((float)(deg + 1));  // +1 self-loop
    }
    // per-(node,shard) start offsets (overwrite h2 with starts)
    int run = lo;
#pragma unroll
    for (int i = 0; i < 8; i++) { h2[t * 8 + i] = run; run += v[i]; }
    __syncthreads();
    for (int e = e0 + t; e < e1; e += 256) {
        uint2 p = ebuf[e];
        int idx = (p.y & 255) * 8 + (p.x >> 14);
        int pos = atomicAdd(&lc2[idx], 1);
        csr[h2[idx] + pos] = (int)p.x;
    }
}

// ---------------- layer-1 aggregation (fp16 gather): aggXh[n] = fp16(dn*(dn*X[n] + sum ds*X[s])) ----------------
__global__ __launch_bounds__(256) void k_agg1(
        const uint2* __restrict__ Xh, const float* __restrict__ dinv,
        const int* __restrict__ offs, const int* __restrict__ cnt,
        const int* __restrict__ csr, int N, uint2* __restrict__ aggXh) {
    int tid = blockIdx.x * blockDim.x + threadIdx.x;
    int n = tid >> 4;
    int f = tid & 15;
    if (n >= N) return;
    float dn = dinv[n];
    float ax, ay, az, aw;
    {
        uint2 p = Xh[(size_t)n * 16 + f];
        __half2 lo = *(__half2*)&p.x, hi = *(__half2*)&p.y;
        ax = dn * __low2float(lo); ay = dn * __high2float(lo);
        az = dn * __low2float(hi); aw = dn * __high2float(hi);
    }
    int base = offs[n], deg = cnt[n];
    int j = 0;
    for (; j + 4 <= deg; j += 4) {
        int s0 = csr[base + j];
        int s1 = csr[base + j + 1];
        int s2 = csr[base + j + 2];
        int s3 = csr[base + j + 3];
        s0 = ((unsigned)s0 < (unsigned)N) ? s0 : 0;
        s1 = ((unsigned)s1 < (unsigned)N) ? s1 : 0;
        s2 = ((unsigned)s2 < (unsigned)N) ? s2 : 0;
        s3 = ((unsigned)s3 < (unsigned)N) ? s3 : 0;
        float w0 = dinv[s0], w1 = dinv[s1], w2 = dinv[s2], w3 = dinv[s3];
        uint2 p0 = Xh[(size_t)s0 * 16 + f];
        uint2 p1 = Xh[(size_t)s1 * 16 + f];
        uint2 p2 = Xh[(size_t)s2 * 16 + f];
        uint2 p3 = Xh[(size_t)s3 * 16 + f];
        __half2 l0 = *(__half2*)&p0.x, h0 = *(__half2*)&p0.y;
        __half2 l1 = *(__half2*)&p1.x, h1 = *(__half2*)&p1.y;
        __half2 l2 = *(__half2*)&p2.x, h2 = *(__half2*)&p2.y;
        __half2 l3 = *(__half2*)&p3.x, h3 = *(__half2*)&p3.y;
        ax += w0 * __low2float(l0) + w1 * __low2float(l1) + w2 * __low2float(l2) + w3 * __low2float(l3);
        ay += w0 * __high2float(l0) + w1 * __high2float(l1) + w2 * __high2float(l2) + w3 * __high2float(l3);
        az += w0 * __low2float(h0) + w1 * __low2float(h1) + w2 * __low2float(h2) + w3 * __low2float(h3);
        aw += w0 * __high2float(h0) + w1 * __high2float(h1) + w2 * __high2float(h2) + w3 * __high2float(h3);
    }
    for (; j < deg; j++) {
        int s0 = csr[base + j];
        s0 = ((unsigned)s0 < (unsigned)N) ? s0 : 0;
        float w0 = dinv[s0];
        uint2 p = Xh[(size_t)s0 * 16 + f];
        __half2 lo = *(__half2*)&p.x, hi = *(__half2*)&p.y;
        ax += w0 * __low2float(lo); ay += w0 * __high2float(lo);
        az += w0 * __low2float(hi); aw += w0 * __high2float(hi);
    }
    __half2 olo = __floats2half2_rn(dn * ax, dn * ay);
    __half2 ohi = __floats2half2_rn(dn * az, dn * aw);
    uint2 o;
    o.x = *(unsigned*)&olo;
    o.y = *(unsigned*)&ohi;
    aggXh[(size_t)n * 16 + f] = o;
}

// ---------------- MFMA MLP: h = elu(t@[Wn|Ws]+b); Zs = half(dn * h@Wf) ----------------
__global__ __launch_bounds__(256) void k_mlp(
        const _Float16* __restrict__ aggXh, const float* __restrict__ dinv,
        const float* __restrict__ Wn, const float* __restrict__ bn,
        const float* __restrict__ Ws, const float* __restrict__ bs,
        const float* __restrict__ Wf, int N, _Float16* __restrict__ Zs) {
    __shared__ half8 sB2[32 * 64];
    __shared__ _Float16 Hbuf[4][16 * 136];

    const int l = threadIdx.x & 63;
    const int wid = threadIdx.x >> 6;
    const int q = l >> 4;
    const int n16 = l & 15;

    for (int e = threadIdx.x; e < 32 * 64; e += 256) {
        int tile = e >> 6, le = e & 63;
        int kt = tile >> 2, nt = tile & 3;
        int qq = le >> 4, nn = le & 15;
        half8 v;
#pragma unroll
        for (int j = 0; j < 8; j++)
            v[j] = (_Float16)Wf[(kt * 32 + qq * 8 + j) * 64 + nt * 16 + nn];
        sB2[e] = v;
    }
    __syncthreads();

    half8 w1n[8], w1s[8];
#pragma unroll
    for (int nt = 0; nt < 8; nt++) {
        half8 a, b;
#pragma unroll
        for (int j = 0; j < 8; j++) {
            a[j] = (_Float16)Wn[(q * 8 + j) * 128 + nt * 16 + n16];
            b[j] = (_Float16)Ws[(q * 8 + j) * 128 + nt * 16 + n16];
        }
        w1n[nt] = a;
        w1s[nt] = b;
    }
    float bnr[8], bsr[8];
#pragma unroll
    for (int nt = 0; nt < 8; nt++) {
        bnr[nt] = bn[nt * 16 + n16];
        bsr[nt] = bs[nt * 16 + n16];
    }

    const int ntiles = (N + 15) >> 4;
    const int nw = gridDim.x * 4;
    _Float16* Hw = Hbuf[wid];

    for (int tile = blockIdx.x * 4 + wid; tile < ntiles; tile += nw) {
        int nb = tile << 4;
        int nodeA = nb + n16;
        if (nodeA >= N) nodeA = N - 1;
        float dn = dinv[nodeA];
        half8 an = *(const half8*)&aggXh[(size_t)nodeA * 64 + q * 8];
        half8 as = *(const half8*)&aggXh[(size_t)nodeA * 64 + 32 + q * 8];

        f32x4 Y[4];
#pragma unroll
        for (int i = 0; i < 4; i++) Y[i] = (f32x4){0.f, 0.f, 0.f, 0.f};

        f32x4 c1[8];
#pragma unroll
        for (int nt = 0; nt < 8; nt++)
            c1[nt] = __builtin_amdgcn_mfma_f32_16x16x32_f16(an, w1n[nt], (f32x4){0.f, 0.f, 0.f, 0.f}, 0, 0, 0);
#pragma unroll
        for (int nt = 0; nt < 8; nt++) {
#pragma unroll
            for (int r = 0; r < 4; r++) {
                float v = c1[nt][r] + bnr[nt];
                v = v > 0.f ? v : expm1f(v);
                Hw[(q * 4 + r) * 136 + nt * 16 + n16] = (_Float16)v;
            }
        }
#pragma unroll
        for (int kt = 0; kt < 4; kt++) {
            half8 ha = *(const half8*)&Hw[n16 * 136 + kt * 32 + q * 8];
#pragma unroll
            for (int nt2 = 0; nt2 < 4; nt2++)
                Y[nt2] = __builtin_amdgcn_mfma_f32_16x16x32_f16(ha, sB2[(kt * 4 + nt2) * 64 + l], Y[nt2], 0, 0, 0);
        }
#pragma unroll
        for (int nt = 0; nt < 8; nt++)
            c1[nt] = __builtin_amdgcn_mfma_f32_16x16x32_f16(as, w1s[nt], (f32x4){0.f, 0.f, 0.f, 0.f}, 0, 0, 0);
#pragma unroll
        for (int nt = 0; nt < 8; nt++) {
#pragma unroll
            for (int r = 0; r < 4; r++) {
                float v = c1[nt][r] + bsr[nt];
                v = v > 0.f ? v : expm1f(v);
                Hw[(q * 4 + r) * 136 + nt * 16 + n16] = (_Float16)v;
            }
        }
#pragma unroll
        for (int kt = 0; kt < 4; kt++) {
            half8 ha = *(const half8*)&Hw[n16 * 136 + kt * 32 + q * 8];
#pragma unroll
            for (int nt2 = 0; nt2 < 4; nt2++)
                Y[nt2] = __builtin_amdgcn_mfma_f32_16x16x32_f16(ha, sB2[((4 + kt) * 4 + nt2) * 64 + l], Y[nt2], 0, 0, 0);
        }
        float dnr[4];
#pragma unroll
        for (int r = 0; r < 4; r++) dnr[r] = __shfl(dn, q * 4 + r);
#pragma unroll
        for (int r = 0; r < 4; r++) {
            int node = nb + q * 4 + r;
            if (node < N) {
#pragma unroll
                for (int nt2 = 0; nt2 < 4; nt2++)
                    Zs[(size_t)node * 64 + nt2 * 16 + n16] = (_Float16)(dnr[r] * Y[nt2][r]);
            }
        }
    }
}

// ---------------- layer-2 aggregation + bias + softmax ----------------
__global__ __launch_bounds__(256) void k_agg2(
        const uint2* __restrict__ Zu, const float* __restrict__ dinv,
        const int* __restrict__ offs, const int* __restrict__ cnt,
        const int* __restrict__ csr, const float4* __restrict__ bias4,
        int N, float4* __restrict__ out4) {
    int tid = blockIdx.x * blockDim.x + threadIdx.x;
    int n = tid >> 4;
    int f = tid & 15;
    if (n >= N) return;
    float ax = 0.f, ay = 0.f, az = 0.f, aw = 0.f;
    {
        uint2 p = Zu[(size_t)n * 16 + f];
        __half2 lo = *(__half2*)&p.x, hi = *(__half2*)&p.y;
        ax = __low2float(lo); ay = __high2float(lo);
        az = __low2float(hi); aw = __high2float(hi);
    }
    int base = offs[n], deg = cnt[n];
    int j = 0;
    for (; j + 4 <= deg; j += 4) {
        int s0 = csr[base + j];
        int s1 = csr[base + j + 1];
        int s2 = csr[base + j + 2];
        int s3 = csr[base + j + 3];
        s0 = ((unsigned)s0 < (unsigned)N) ? s0 : 0;
        s1 = ((unsigned)s1 < (unsigned)N) ? s1 : 0;
        s2 = ((unsigned)s2 < (unsigned)N) ? s2 : 0;
        s3 = ((unsigned)s3 < (unsigned)N) ? s3 : 0;
        uint2 p0 = Zu[(size_t)s0 * 16 + f];
        uint2 p1 = Zu[(size_t)s1 * 16 + f];
        uint2 p2 = Zu[(size_t)s2 * 16 + f];
        uint2 p3 = Zu[(size_t)s3 * 16 + f];
#pragma unroll
        for (int k = 0; k < 4; k++) {
            uint2 p = (k == 0) ? p0 : (k == 1) ? p1 : (k == 2) ? p2 : p3;
            __half2 lo = *(__half2*)&p.x, hi = *(__half2*)&p.y;
            ax += __low2float(lo); ay += __high2float(lo);
            az += __low2float(hi); aw += __high2float(hi);
        }
    }
    for (; j < deg; j++) {
        int s0 = csr[base + j];
        s0 = ((unsigned)s0 < (unsigned)N) ? s0 : 0;
        uint2 p = Zu[(size_t)s0 * 16 + f];
        __half2 lo = *(__half2*)&p.x, hi = *(__half2*)&p.y;
        ax += __low2float(lo); ay += __high2float(lo);
        az += __low2float(hi); aw += __high2float(hi);
    }
    float dn = dinv[n];
    float4 b = bias4[f];
    ax = dn * ax + b.x; ay = dn * ay + b.y; az = dn * az + b.z; aw = dn * aw + b.w;
    float mx = fmaxf(fmaxf(ax, ay), fmaxf(az, aw));
    for (int o = 8; o >= 1; o >>= 1) mx = fmaxf(mx, __shfl_xor(mx, o));
    float ex = expf(ax - mx), ey = expf(ay - mx), ez = expf(az - mx), ew = expf(aw - mx);
    float sm = ex + ey + ez + ew;
    for (int o = 8; o >= 1; o >>= 1) sm += __shfl_xor(sm, o);
    float inv = 1.f / sm;
    out4[(size_t)n * 16 + f] = make_float4(ex * inv, ey * inv, ez * inv, ew * inv);
}

extern "C" void kernel_launch(void* const* d_in, const int* in_sizes, int n_in,
                              void* d_out, int out_size, void* d_ws, size_t ws_size,
                              hipStream_t stream) {
    const float* X = (const float*)d_in[0];
    const int* ei = (const int*)d_in[1];
    // d_in[2] = batch (unused)
    const float* Wn = (const float*)d_in[3];
    const float* bn = (const float*)d_in[4];
    const float* Ws = (const float*)d_in[5];
    const float* bs = (const float*)d_in[6];
    const float* Wf = (const float*)d_in[7];
    const float* bfu = (const float*)d_in[8];

    const int N = in_sizes[2];        // 100000
    const int E = in_sizes[1] / 2;    // 1600000
    const int* src = ei;
    const int* dst = ei + E;
    const int NB = (N + 255) >> 8;    // 391 buckets

    // workspace layout (128-aligned); total ~33.2 MB
    char* ws = (char*)d_ws;
    int* bcur     = (int*)(ws + 0);            // NB*8*4 = 12512 -> pad 12800
    int* bstart   = (int*)(ws + 12800);        // (NB+1)*4 -> pad 14464
    int* cnt      = (int*)(ws + 14464);        // 400000 -> 414464
    float* dinv   = (float*)(ws + 414464);     // 400000 -> 814464
    int* offs     = (int*)(ws + 814464);       // 400000 -> 1214464
    int* csr      = (int*)(ws + 1214464);      // 6400000 -> 7614464
    // slot A: ebuf (part/build), then aggXh (agg1 -> mlp)
    uint2* ebuf   = (uint2*)(ws + 7614464);    // 12800000 -> 20414464
    uint2* aggXh  = (uint2*)(ws + 7614464);
    // slot B: Xh (part-tail -> agg1), then Zs (mlp -> agg2)
    uint2* Xh     = (uint2*)(ws + 20414464);   // 12800000 -> 33214464 total
    _Float16* Zs  = (_Float16*)(ws + 20414464);

    hipMemsetAsync(ws, 0, 12800, stream);  // zero bcur only

    int Er = (E + 7) / 8;                 // edges per region
    int sbl = 8 * ((Er + 4095) / 4096);   // swizzled grid for bhist/part
    int M = N * 16;

    k_bhist<<<sbl, 256, NB * 4, stream>>>(dst, E, Er, N, bcur);
    k_bscan<<<1, 1024, 0, stream>>>(bcur, NB * 8, NB, E, bstart);
    k_part<<<sbl, 256, 0, stream>>>(src, dst, E, Er, N, bcur, ebuf, (const float4*)X, M, Xh);
    k_build<<<NB, 256, 0, stream>>>(ebuf, bstart, N, cnt, dinv, offs, csr);

    int gbl = (M + 255) / 256;  // thread-per-(node, chunk)
    k_agg1<<<gbl, 256, 0, stream>>>(Xh, dinv, offs, cnt, csr, N, aggXh);
    k_mlp<<<512, 256, 0, stream>>>((const _Float16*)aggXh, dinv, Wn, bn, Ws, bs, Wf, N, Zs);
    k_agg2<<<gbl, 256, 0, stream>>>((const uint2*)Zs, dinv, offs, cnt, csr,
                                    (const float4*)bfu, N, (float4*)d_out);
}